// Round 13
// baseline (228.384 us; speedup 1.0000x reference)
//
#include <hip/hip_runtime.h>

typedef _Float16 hfrag_t __attribute__((ext_vector_type(8)));   // 8 x f16 (4 VGPRs)
typedef _Float16 h2_t    __attribute__((ext_vector_type(2)));
typedef __attribute__((ext_vector_type(4))) float    f4_t;
typedef __attribute__((ext_vector_type(4))) unsigned u4_t;

#define LOG_2PI   1.8378770664093453f
#define TWO_LOG2  1.3862943611198906f
#define T_TILES   4            // 16-point tiles per wave (state in registers)
#define BLOCK     256          // 4 waves
#define PTS_BLK   256          // 4 waves * 4 tiles * 16 pts
#define ZCLAMP    30000.0f     // keeps h1 = w1*z inside f16 range; only clips tanh-saturated pts

__device__ __forceinline__ unsigned pkh(float a, float b) {
  return __builtin_bit_cast(unsigned, __builtin_amdgcn_cvt_pkrtz(a, b));
}
__device__ __forceinline__ unsigned pk_fma_h(unsigned a, unsigned b, unsigned c) {
  unsigned d;
  asm("v_pk_fma_f16 %0, %1, %2, %3" : "=v"(d) : "v"(a), "v"(b), "v"(c));
  return d;
}
// packed leaky-relu: max(h, 0.01h) on 2 f16 lanes (2 insts)
__device__ __forceinline__ unsigned pk_leaky_h(unsigned h, unsigned k01) {
  unsigned t, r;
  asm("v_pk_mul_f16 %0, %1, %2" : "=v"(t) : "v"(h), "v"(k01));
  asm("v_pk_max_f16 %0, %1, %2" : "=v"(r) : "v"(h), "v"(t));
  return r;
}
__device__ __forceinline__ float dot2h(unsigned a, unsigned b, float c) {
  return __builtin_amdgcn_fdot2(__builtin_bit_cast(h2_t, a), __builtin_bit_cast(h2_t, b), c, false);
}

// Stage one layer's W2 (both MLPs) into LDS as f16 MFMA A-fragments.
// A-frag layout for mfma_f32_16x16x32_f16: lane l holds A[16n + (l&15)][32q + 8*(l>>4) + e], e=0..7
__device__ __forceinline__ void stage_layer(u4_t* afr, const float* sW2, const float* tW2,
                                            int layer, int tid) {
  #pragma unroll
  for (int it = 0; it < 4; ++it) {
    int idx = tid + it * BLOCK;          // 0..1023
    int l = idx & 63, f = (idx >> 6) & 7, m = (idx >> 9) & 1;
    int n = f & 3, q = f >> 2;
    int row = 16 * n + (l & 15), kb = 32 * q + 8 * (l >> 4);
    const float* src = (m ? tW2 : sW2) + layer * 4096 + row * 64 + kb;
    float4 a = *(const float4*)src;
    float4 b = *(const float4*)(src + 4);
    afr[(m * 8 + f) * 64 + l] =
        (u4_t){pkh(a.x, a.y), pkh(a.z, a.w), pkh(b.x, b.y), pkh(b.z, b.w)};
  }
}

__global__ __launch_bounds__(BLOCK)
__attribute__((amdgpu_waves_per_eu(4)))   // min-only: permit up to 128 VGPR
void ihll_kernel(
    const float* __restrict__ pred, const float* __restrict__ targ, const float* __restrict__ twp,
    const float* __restrict__ sW1, const float* __restrict__ sB1, const float* __restrict__ sW2,
    const float* __restrict__ sB2, const float* __restrict__ sW3, const float* __restrict__ sB3,
    const float* __restrict__ tW1, const float* __restrict__ tB1, const float* __restrict__ tW2,
    const float* __restrict__ tB2, const float* __restrict__ tW3, const float* __restrict__ tB3,
    float* __restrict__ out, int M) {
  // LDS: weights only. Flow state lives in REGISTERS (consistent across the
  // 4 lane-groups because all lanes compute the identical update after the
  // butterfly reduce) -> no LDS stores inside a pass -> constant ds_reads
  // are freely CSE'd/hoisted (the R6-R12 alias-analysis wall is gone).
  __shared__ u4_t     afr[2 * 8 * 64];     // 16KB f16 W2 A-frags
  __shared__ unsigned c1h[6][2][32];       // 1.5KB half2(w1)
  __shared__ unsigned b1h[6][2][32];       // 1.5KB half2(b1)
  __shared__ unsigned w3h[6][2][4][8];     // 1.5KB [g][2n+j]: half2 of w3 rows 16n+4g+2j..+1
  __shared__ float    b2s[6][2][64];       // 3KB  b2 fp32 (MFMA C-init)
  __shared__ float    wsum[4];             // ~23.6KB total -> 6 blocks/CU

  const int tid  = threadIdx.x;
  const int lane = tid & 63, wave = tid >> 6;
  const int pr   = lane & 15, g = lane >> 4;
  const int pbase = blockIdx.x * PTS_BLK;
  const unsigned k01h = pkh(0.01f, 0.01f);

  // ---- stage per-layer small tables (all 6 layers, once) ----
  for (int idx = tid; idx < 384; idx += BLOCK) {       // c1h/b1h
    int i = idx >> 6, r = idx & 63, m = r >> 5, jp = r & 31;
    int jo = i & 1, jm = jo ^ 1;                       // MASK[i]: i even -> jm=1, jo=0
    const float* w1 = m ? tW1 : sW1;  const float* b1 = m ? tB1 : sB1;
    c1h[i][m][jp] = pkh(w1[i * 128 + 4 * jp + jm], w1[i * 128 + 4 * jp + 2 + jm]);
    b1h[i][m][jp] = pkh(b1[i * 64 + 2 * jp], b1[i * 64 + 2 * jp + 1]);
  }
  for (int idx = tid; idx < 384; idx += BLOCK) {       // w3h
    int i = idx >> 6, r = idx & 63, m = r >> 5, c = r & 31;
    int gg = c >> 3, c2 = c & 7, n = c2 >> 1, jj = c2 & 1;
    int jo = i & 1;
    const float* w3 = m ? tW3 : sW3;
    int row = 16 * n + 4 * gg + 2 * jj;
    w3h[i][m][gg][c2] = pkh(w3[i * 128 + jo * 64 + row], w3[i * 128 + jo * 64 + row + 1]);
  }
  for (int idx = tid; idx < 768; idx += BLOCK) {       // b2s
    int i = idx >> 7, r = idx & 127, m = r >> 6, j = r & 63;
    const float* b2 = m ? tB2 : sB2;
    b2s[i][m][j] = b2[i * 64 + j];
  }

  // ---- per-lane register flow state (replicated over the 4 lane-groups) ----
  float z0[T_TILES], z1[T_TILES], ld[T_TILES], pre0[T_TILES];
  #pragma unroll
  for (int t = 0; t < T_TILES; ++t) {
    int P = pbase + wave * 64 + t * 16 + pr;
    float e0 = 0.f, e1 = 0.f;
    if (P < M) {
      float4 p4 = ((const float4*)pred)[P];
      float2 t2 = ((const float2*)targ)[P];
      float s0 = sqrtf(fabsf(p4.z)), s1 = sqrtf(fabsf(p4.w));
      e0 = (p4.x - t2.x) / (s0 + 1e-9f);
      e1 = (p4.y - t2.y) / (s1 + 1e-9f);
    }
    z0[t] = e0; z1[t] = e1; ld[t] = 0.f; pre0[t] = 0.f;
  }
  stage_layer(afr, sW2, tW2, 5, tid);   // first layer processed is i=5
  __syncthreads();

  // ---- layer loop: i = 5..0 ----
  #pragma unroll 1
  for (int li = 0; li < 6; ++li) {
    const int i = 5 - li;
    const int jo = i & 1;             // component written this layer
    const bool upd0 = (jo == 0);      // jo==0: input comp is z1, output z0
    const float b3s = sB3[i * 2 + jo];
    const float b3t = tB3[i * 2 + jo];

    // ---- two passes (compile-time m): m=0 s-net (pre0 in regs), m=1 t-net ----
    #pragma unroll
    for (int m = 0; m < 2; ++m) {
      // per-pass constants: no LDS stores follow in this pass -> hoistable
      u4_t af[8];
      #pragma unroll
      for (int f = 0; f < 8; ++f)
        af[f] = afr[(m * 8 + f) * 64 + lane];
      unsigned c1q[8], b1q[8];
      *(u4_t*)&c1q[0] = *(const u4_t*)&c1h[i][m][4 * g];
      *(u4_t*)&c1q[4] = *(const u4_t*)&c1h[i][m][16 + 4 * g];
      *(u4_t*)&b1q[0] = *(const u4_t*)&b1h[i][m][4 * g];
      *(u4_t*)&b1q[4] = *(const u4_t*)&b1h[i][m][16 + 4 * g];
      unsigned w3q[8];
      *(u4_t*)&w3q[0] = *(const u4_t*)&w3h[i][m][g][0];
      *(u4_t*)&w3q[4] = *(const u4_t*)&w3h[i][m][g][4];
      f4_t b2q[4];
      #pragma unroll
      for (int n = 0; n < 4; ++n)
        b2q[n] = *(const f4_t*)&b2s[i][m][n * 16 + 4 * g];

      // ---- tile loop: fully unrolled, ZERO LDS traffic ----
      #pragma unroll
      for (int t = 0; t < T_TILES; ++t) {
        float zin = upd0 ? z1[t] : z0[t];
        zin = fmaxf(fminf(zin, ZCLAMP), -ZCLAMP);
        const unsigned zz = pkh(zin, zin);

        f4_t acc[4];
        #pragma unroll
        for (int q = 0; q < 2; ++q) {
          unsigned hh[4];
          #pragma unroll
          for (int e = 0; e < 4; ++e)
            hh[e] = pk_leaky_h(pk_fma_h(c1q[q * 4 + e], zz, b1q[q * 4 + e]), k01h);
          hfrag_t B = __builtin_bit_cast(hfrag_t, (u4_t){hh[0], hh[1], hh[2], hh[3]});
          #pragma unroll
          for (int n = 0; n < 4; ++n) {
            f4_t c = (q == 0) ? b2q[n] : acc[n];   // b2 folded into first MFMA
            acc[n] = __builtin_amdgcn_mfma_f32_16x16x32_f16(
                __builtin_bit_cast(hfrag_t, af[q * 4 + n]), B, c, 0, 0, 0);
          }
        }
        // layer 3: leaky(h2) . w3, split (2-deep) dot chains
        float pa_ = 0.f, pb_ = 0.f;
        #pragma unroll
        for (int n = 0; n < 4; ++n) {
          unsigned a01 = pk_leaky_h(pkh(acc[n][0], acc[n][1]), k01h);
          unsigned a23 = pk_leaky_h(pkh(acc[n][2], acc[n][3]), k01h);
          if (n < 2) {
            pa_ = dot2h(a01, w3q[2 * n], pa_);
            pa_ = dot2h(a23, w3q[2 * n + 1], pa_);
          } else {
            pb_ = dot2h(a01, w3q[2 * n], pb_);
            pb_ = dot2h(a23, w3q[2 * n + 1], pb_);
          }
        }
        float pt = pa_ + pb_;
        pt += __shfl_xor(pt, 16);
        pt += __shfl_xor(pt, 32);      // all 64 lanes now hold the full sum

        if (m == 0) {
          pre0[t] = pt;                // register hand-off to the t-net pass
        } else {
          // coupling update: computed identically by ALL lanes -> the 4
          // register copies stay consistent with no communication.
          float sv = 1.f - 2.f / (__expf(2.f * (pre0[t] + b3s)) + 1.f);  // tanh
          float tv = pt + b3t;
          float zo = upd0 ? z0[t] : z1[t];
          float zn = (zo - tv) * __expf(-sv);
          if (upd0) z0[t] = zn; else z1[t] = zn;
          ld[t] -= sv;
        }
      }
    }
    __syncthreads();
    if (li < 5) {
      stage_layer(afr, sW2, tW2, i - 1, tid);
      __syncthreads();
    }
  }

  // ---- epilogue: recompute base term from global, add prior + logdet ----
  float csum = 0.f;
  #pragma unroll
  for (int t = 0; t < T_TILES; ++t) {
    int P = pbase + wave * 64 + t * 16 + pr;
    if (P < M) {
      float4 p4 = ((const float4*)pred)[P];
      float2 t2 = ((const float2*)targ)[P];
      float w   = twp[P];
      float s0 = sqrtf(fabsf(p4.z)), s1 = sqrtf(fabsf(p4.w));
      float e0 = (p4.x - t2.x) / (s0 + 1e-9f);
      float e1 = (p4.y - t2.y) / (s1 + 1e-9f);
      float bs = 2.f * (logf(s0) + logf(s1)) + TWO_LOG2 + fabsf(e0) + fabsf(e1);
      float prior = -0.5f * (z0[t] * z0[t] + z1[t] * z1[t]) - LOG_2PI;
      float lphi  = prior + ld[t];
      csum += (bs - 2.f * lphi) * w;
    }
  }
  // butterfly over all 64 lanes (4 group-copies of each point -> /4 later)
  #pragma unroll
  for (int off = 1; off <= 32; off <<= 1)
    csum += __shfl_xor(csum, off);
  if (lane == 0) wsum[wave] = csum;
  __syncthreads();
  if (tid == 0) {
    float tot = wsum[0] + wsum[1] + wsum[2] + wsum[3];
    atomicAdd(out, tot * (1.0f / 32768.0f));   // /4 replication, /8192 batch
  }
}

extern "C" void kernel_launch(void* const* d_in, const int* in_sizes, int n_in,
                              void* d_out, int out_size, void* d_ws, size_t ws_size,
                              hipStream_t stream) {
  const float* pred = (const float*)d_in[0];
  const float* targ = (const float*)d_in[1];
  const float* twp  = (const float*)d_in[2];
  const float* sW1 = (const float*)d_in[3];  const float* sB1 = (const float*)d_in[4];
  const float* sW2 = (const float*)d_in[5];  const float* sB2 = (const float*)d_in[6];
  const float* sW3 = (const float*)d_in[7];  const float* sB3 = (const float*)d_in[8];
  const float* tW1 = (const float*)d_in[9];  const float* tB1 = (const float*)d_in[10];
  const float* tW2 = (const float*)d_in[11]; const float* tB2 = (const float*)d_in[12];
  const float* tW3 = (const float*)d_in[13]; const float* tB3 = (const float*)d_in[14];

  const int M = in_sizes[2];               // N*K points
  const int blocks = (M + PTS_BLK - 1) / PTS_BLK;

  hipMemsetAsync(d_out, 0, sizeof(float), stream);
  hipLaunchKernelGGL(ihll_kernel, dim3(blocks), dim3(BLOCK), 0, stream,
                     pred, targ, twp, sW1, sB1, sW2, sB2, sW3, sB3,
                     tW1, tB1, tW2, tB2, tW3, tB3, (float*)d_out, M);
}